// Round 11
// baseline (368.353 us; speedup 1.0000x reference)
//
#include <hip/hip_runtime.h>

typedef float f32x2 __attribute__((ext_vector_type(2)));
typedef unsigned int u32;

#define NIT 21
#define SMIN 1e-33f

// DPP quad-perm / row-rotate all-reduce over each 16-lane group (VALU pipe).
template<int CTRL>
static __device__ __forceinline__ float dppmov(float v) {
    return __int_as_float(__builtin_amdgcn_mov_dpp(__float_as_int(v), CTRL, 0xF, 0xF, true));
}
static __device__ __forceinline__ float sum16(float v) {
    v += dppmov<0xB1>(v);    // xor1
    v += dppmov<0x4E>(v);    // xor2
    v += dppmov<0x124>(v);   // row_ror:4
    v += dppmov<0x128>(v);   // row_ror:8
    return v;
}
static __device__ __forceinline__ float max16(float v) {
    v = fmaxf(v, dppmov<0xB1>(v));
    v = fmaxf(v, dppmov<0x4E>(v));
    v = fmaxf(v, dppmov<0x124>(v));
    v = fmaxf(v, dppmov<0x128>(v));
    return v;
}

#if __has_builtin(__builtin_amdgcn_permlane16_swap) && __has_builtin(__builtin_amdgcn_permlane32_swap)
#define HAVE_PLSWAP 1
// validated on HW in round 10
static __device__ __forceinline__ float plsum16(float A, float B) {
    auto r = __builtin_amdgcn_permlane16_swap(__float_as_uint(A), __float_as_uint(B), false, false);
    return __uint_as_float(r[0]) + __uint_as_float(r[1]);
}
static __device__ __forceinline__ float plsum32(float X, float Y) {
    auto r = __builtin_amdgcn_permlane32_swap(__float_as_uint(X), __float_as_uint(Y), false, false);
    return __uint_as_float(r[0]) + __uint_as_float(r[1]);
}
#else
#define HAVE_PLSWAP 0
#endif

// One 256-thread block per 128x128 matrix (8x8 tile/thread). Linear-space
// Sinkhorn: E = 2^((x-m)*S) fixed in registers; lazy rcp factors a_i/b_j.
// Round-11: __launch_bounds__(256,6) caps total regs (VGPR+AGPR) at ~85 so
// E (64 floats) + working set stays AGPR-free -> 6 waves/SIMD (was ~4 with
// E in AGPRs at cap 170). 32-bit addressing (67.1M elems < 2^32). Col-phase
// math in f32x2 so the compiler can form v_pk_fma_f32 (no inline asm).
__global__ __launch_bounds__(256, 6) void sinkhorn_kernel(const float* __restrict__ in,
                                                          float* __restrict__ out) {
    const int t  = threadIdx.x;
    const int rg = t >> 4;      // row-group 0..15 (rows rg*8..+7)
    const int cg = t & 15;      // col-group (cols cg*8..+7); == lane&15
    const int wv = t >> 6;      // wave 0..3
    const int q  = rg & 3;      // 16-lane row index within wave
    const u32 off = ((u32)blockIdx.x << 14) + ((u32)rg << 10) + ((u32)cg << 3);
    const float* __restrict__ src = in  + off;
    float*       __restrict__ dst = out + off;

    const float S = 36.067376022224085f;  // (1/0.04) * log2(e)

    f32x2 E[8][4];
    float a[8];
    f32x2 b2[4];

    // ---- init: row max, E = 2^((x-m)*S), a = rcp(rowsum) ----
#pragma unroll
    for (int i = 0; i < 8; ++i) {
        float4 f0 = *(const float4*)(src + (i << 7));
        float4 f1 = *(const float4*)(src + (i << 7) + 4);
        E[i][0] = (f32x2){f0.x, f0.y};
        E[i][1] = (f32x2){f0.z, f0.w};
        E[i][2] = (f32x2){f1.x, f1.y};
        E[i][3] = (f32x2){f1.z, f1.w};
        f32x2 m2 = E[i][0];
#pragma unroll
        for (int j = 1; j < 4; ++j) {
            m2.x = fmaxf(m2.x, E[i][j].x);
            m2.y = fmaxf(m2.y, E[i][j].y);
        }
        float m = max16(fmaxf(m2.x, m2.y));
        const float nms = -m * S;
        float s = 0.f;
#pragma unroll
        for (int j = 0; j < 4; ++j) {
            f32x2 e;
            e.x = __builtin_amdgcn_exp2f(fmaf(E[i][j].x, S, nms));
            e.y = __builtin_amdgcn_exp2f(fmaf(E[i][j].y, S, nms));
            E[i][j] = e;
            s += e.x + e.y;
        }
        s = sum16(s);
        a[i] = __builtin_amdgcn_rcpf(fmaxf(s, SMIN));   // rowsum in [1,128]
    }

    // col partials: [dbuf][wave][128 floats]; float idx cg*4+q (cols 0..3 of
    // group cg) and 64+cg*4+q (cols 4..7) -> float4 readback at idx cg, 16+cg.
    __shared__ float part[2][4][128];
    int pb = 0;

#pragma unroll 1
    for (int it = 0; it < NIT; ++it) {
        // ---- col phase: b_j = rcp( sum_i E_ij * a_i ) ----
        f32x2 sc[4];
#pragma unroll
        for (int j = 0; j < 4; ++j) sc[j] = (f32x2){0.f, 0.f};
#pragma unroll
        for (int i = 0; i < 8; ++i) {
            const f32x2 ai2 = {a[i], a[i]};
#pragma unroll
            for (int j = 0; j < 4; ++j) sc[j] += E[i][j] * ai2;
        }
#if HAVE_PLSWAP
        // in-wave reduce over the 4 row-groups, all VALU (validated r10)
        float s01 = plsum16(sc[0].x, sc[0].y);
        float s23 = plsum16(sc[1].x, sc[1].y);
        float s45 = plsum16(sc[2].x, sc[2].y);
        float s67 = plsum16(sc[3].x, sc[3].y);
        float X1 = plsum32(s01, s23);
        float X2 = plsum32(s45, s67);
        part[pb][wv][(cg << 2) + q]      = X1;
        part[pb][wv][64 + (cg << 2) + q] = X2;
#else
#pragma unroll
        for (int j = 0; j < 4; ++j) {
            sc[j].x += __shfl_xor(sc[j].x, 16); sc[j].y += __shfl_xor(sc[j].y, 16);
            sc[j].x += __shfl_xor(sc[j].x, 32); sc[j].y += __shfl_xor(sc[j].y, 32);
        }
        if ((t & 63) < 16) {
            float4* p4 = (float4*)part[pb][wv];
            p4[cg]      = make_float4(sc[0].x, sc[0].y, sc[1].x, sc[1].y);
            p4[16 + cg] = make_float4(sc[2].x, sc[2].y, sc[3].x, sc[3].y);
        }
#endif
        __syncthreads();
        {
            const float4* p0 = (const float4*)part[pb][0];
            const float4* p1 = (const float4*)part[pb][1];
            const float4* p2 = (const float4*)part[pb][2];
            const float4* p3 = (const float4*)part[pb][3];
            float4 lo = p0[cg];
            float4 hi = p0[16 + cg];
            float4 l1 = p1[cg], h1 = p1[16 + cg];
            float4 l2 = p2[cg], h2 = p2[16 + cg];
            float4 l3 = p3[cg], h3 = p3[16 + cg];
            lo.x += l1.x + l2.x + l3.x; lo.y += l1.y + l2.y + l3.y;
            lo.z += l1.z + l2.z + l3.z; lo.w += l1.w + l2.w + l3.w;
            hi.x += h1.x + h2.x + h3.x; hi.y += h1.y + h2.y + h3.y;
            hi.z += h1.z + h2.z + h3.z; hi.w += h1.w + h2.w + h3.w;
            b2[0].x = __builtin_amdgcn_rcpf(fmaxf(lo.x, SMIN));
            b2[0].y = __builtin_amdgcn_rcpf(fmaxf(lo.y, SMIN));
            b2[1].x = __builtin_amdgcn_rcpf(fmaxf(lo.z, SMIN));
            b2[1].y = __builtin_amdgcn_rcpf(fmaxf(lo.w, SMIN));
            b2[2].x = __builtin_amdgcn_rcpf(fmaxf(hi.x, SMIN));
            b2[2].y = __builtin_amdgcn_rcpf(fmaxf(hi.y, SMIN));
            b2[3].x = __builtin_amdgcn_rcpf(fmaxf(hi.z, SMIN));
            b2[3].y = __builtin_amdgcn_rcpf(fmaxf(hi.w, SMIN));
        }
        pb ^= 1;

        // ---- row phase: a_i = rcp( sum_j E_ij * b_j )  (skip after last col) ----
        if (it < NIT - 1) {
#pragma unroll
            for (int i = 0; i < 8; ++i) {
                f32x2 s2 = E[i][0] * b2[0];
                s2 += E[i][1] * b2[1];
                s2 += E[i][2] * b2[2];
                s2 += E[i][3] * b2[3];
                float s = sum16(s2.x + s2.y);
                a[i] = __builtin_amdgcn_rcpf(fmaxf(s, SMIN));
            }
        }
    }

    // ---- epilogue: out = E * a_i * b_j ----
#pragma unroll
    for (int i = 0; i < 8; ++i) {
        const float ai = a[i];
        f32x2 p0 = E[i][0] * b2[0];
        f32x2 p1 = E[i][1] * b2[1];
        f32x2 p2 = E[i][2] * b2[2];
        f32x2 p3 = E[i][3] * b2[3];
        float4 o0 = make_float4(p0.x * ai, p0.y * ai, p1.x * ai, p1.y * ai);
        float4 o1 = make_float4(p2.x * ai, p2.y * ai, p3.x * ai, p3.y * ai);
        *(float4*)(dst + (i << 7))     = o0;
        *(float4*)(dst + (i << 7) + 4) = o1;
    }
}

extern "C" void kernel_launch(void* const* d_in, const int* in_sizes, int n_in,
                              void* d_out, int out_size, void* d_ws, size_t ws_size,
                              hipStream_t stream) {
    (void)n_in; (void)d_ws; (void)ws_size; (void)out_size;
    const float* in  = (const float*)d_in[0];
    float*       out = (float*)d_out;
    const int n_mat = in_sizes[0] / (128 * 128);  // 4096
    sinkhorn_kernel<<<dim3(n_mat), dim3(256), 0, stream>>>(in, out);
}

// Round 12
// 166.986 us; speedup vs baseline: 2.2059x; 2.2059x over previous
//
#include <hip/hip_runtime.h>

typedef float f32x2 __attribute__((ext_vector_type(2)));
typedef unsigned int u32;

#define NIT 21
#define SMIN 1e-33f

// DPP quad-perm / row-rotate all-reduce over each 16-lane group (VALU pipe).
template<int CTRL>
static __device__ __forceinline__ float dppmov(float v) {
    return __int_as_float(__builtin_amdgcn_mov_dpp(__float_as_int(v), CTRL, 0xF, 0xF, true));
}
static __device__ __forceinline__ float sum16(float v) {
    v += dppmov<0xB1>(v);    // xor1
    v += dppmov<0x4E>(v);    // xor2
    v += dppmov<0x124>(v);   // row_ror:4
    v += dppmov<0x128>(v);   // row_ror:8
    return v;
}
static __device__ __forceinline__ float max16(float v) {
    v = fmaxf(v, dppmov<0xB1>(v));
    v = fmaxf(v, dppmov<0x4E>(v));
    v = fmaxf(v, dppmov<0x124>(v));
    v = fmaxf(v, dppmov<0x128>(v));
    return v;
}

#if __has_builtin(__builtin_amdgcn_permlane16_swap) && __has_builtin(__builtin_amdgcn_permlane32_swap)
#define HAVE_PLSWAP 1
// validated on HW in round 10
static __device__ __forceinline__ float plsum16(float A, float B) {
    auto r = __builtin_amdgcn_permlane16_swap(__float_as_uint(A), __float_as_uint(B), false, false);
    return __uint_as_float(r[0]) + __uint_as_float(r[1]);
}
static __device__ __forceinline__ float plsum32(float X, float Y) {
    auto r = __builtin_amdgcn_permlane32_swap(__float_as_uint(X), __float_as_uint(Y), false, false);
    return __uint_as_float(r[0]) + __uint_as_float(r[1]);
}
#else
#define HAVE_PLSWAP 0
#endif

// One 256-thread block per 128x128 matrix (8x8 tile/thread). Linear-space
// Sinkhorn: E = 2^((x-m)*S) fixed in registers; lazy rcp factors a_i/b_j.
// Round-12: amdgpu_waves_per_eu(4,4) pins the occupancy target so the
// allocator stops minimizing arch VGPRs (which exiled E to AGPRs with
// accvgpr shuttles on every access in r2-r11's passing kernels; VGPR_Count
// 52-56 < the 64 live floats of E proved it). Budget 512/4 = 128 regs;
// need ~104 -> E stays in arch VGPRs, no shuttles, no spill.
// r11 lesson: cap 85 forced scratch spill (FETCH 131->237MB) - 4 waves is
// the tightest safe cap. Arithmetic identical to r10 (validated).
__global__ void __attribute__((amdgpu_flat_work_group_size(256, 256),
                               amdgpu_waves_per_eu(4, 4)))
sinkhorn_kernel(const float* __restrict__ in, float* __restrict__ out) {
    const int t  = threadIdx.x;
    const int rg = t >> 4;      // row-group 0..15 (rows rg*8..+7)
    const int cg = t & 15;      // col-group (cols cg*8..+7); == lane&15
    const int wv = t >> 6;      // wave 0..3
    const int q  = rg & 3;      // 16-lane row index within wave
    const u32 off = ((u32)blockIdx.x << 14) + ((u32)rg << 10) + ((u32)cg << 3);
    const float* __restrict__ src = in  + off;
    float*       __restrict__ dst = out + off;

    const float S = 36.067376022224085f;  // (1/0.04) * log2(e)

    f32x2 E[8][4];
    float a[8];
    f32x2 b2[4];

    // ---- init: row max, E = 2^((x-m)*S), a = rcp(rowsum) ----
#pragma unroll
    for (int i = 0; i < 8; ++i) {
        float4 f0 = *(const float4*)(src + (i << 7));
        float4 f1 = *(const float4*)(src + (i << 7) + 4);
        E[i][0] = (f32x2){f0.x, f0.y};
        E[i][1] = (f32x2){f0.z, f0.w};
        E[i][2] = (f32x2){f1.x, f1.y};
        E[i][3] = (f32x2){f1.z, f1.w};
        f32x2 m2 = E[i][0];
#pragma unroll
        for (int j = 1; j < 4; ++j) {
            m2.x = fmaxf(m2.x, E[i][j].x);
            m2.y = fmaxf(m2.y, E[i][j].y);
        }
        float m = max16(fmaxf(m2.x, m2.y));
        const float nms = -m * S;
        float s = 0.f;
#pragma unroll
        for (int j = 0; j < 4; ++j) {
            f32x2 e;
            e.x = __builtin_amdgcn_exp2f(fmaf(E[i][j].x, S, nms));
            e.y = __builtin_amdgcn_exp2f(fmaf(E[i][j].y, S, nms));
            E[i][j] = e;
            s += e.x + e.y;
        }
        s = sum16(s);
        a[i] = __builtin_amdgcn_rcpf(fmaxf(s, SMIN));   // rowsum in [1,128]
    }

    // col partials: [dbuf][wave][128 floats]; float idx cg*4+q (cols 0..3 of
    // group cg) and 64+cg*4+q (cols 4..7) -> float4 readback at idx cg, 16+cg.
    __shared__ float part[2][4][128];
    int pb = 0;

#pragma unroll 1
    for (int it = 0; it < NIT; ++it) {
        // ---- col phase: b_j = rcp( sum_i E_ij * a_i ) ----
        f32x2 sc[4];
#pragma unroll
        for (int j = 0; j < 4; ++j) sc[j] = (f32x2){0.f, 0.f};
#pragma unroll
        for (int i = 0; i < 8; ++i) {
            const f32x2 ai2 = {a[i], a[i]};
#pragma unroll
            for (int j = 0; j < 4; ++j) sc[j] += E[i][j] * ai2;
        }
#if HAVE_PLSWAP
        // in-wave reduce over the 4 row-groups, all VALU (validated r10)
        float s01 = plsum16(sc[0].x, sc[0].y);
        float s23 = plsum16(sc[1].x, sc[1].y);
        float s45 = plsum16(sc[2].x, sc[2].y);
        float s67 = plsum16(sc[3].x, sc[3].y);
        float X1 = plsum32(s01, s23);
        float X2 = plsum32(s45, s67);
        part[pb][wv][(cg << 2) + q]      = X1;
        part[pb][wv][64 + (cg << 2) + q] = X2;
#else
#pragma unroll
        for (int j = 0; j < 4; ++j) {
            sc[j].x += __shfl_xor(sc[j].x, 16); sc[j].y += __shfl_xor(sc[j].y, 16);
            sc[j].x += __shfl_xor(sc[j].x, 32); sc[j].y += __shfl_xor(sc[j].y, 32);
        }
        if ((t & 63) < 16) {
            float4* p4 = (float4*)part[pb][wv];
            p4[cg]      = make_float4(sc[0].x, sc[0].y, sc[1].x, sc[1].y);
            p4[16 + cg] = make_float4(sc[2].x, sc[2].y, sc[3].x, sc[3].y);
        }
#endif
        __syncthreads();
        {
            const float4* p0 = (const float4*)part[pb][0];
            const float4* p1 = (const float4*)part[pb][1];
            const float4* p2 = (const float4*)part[pb][2];
            const float4* p3 = (const float4*)part[pb][3];
            float4 lo = p0[cg];
            float4 hi = p0[16 + cg];
            float4 l1 = p1[cg], h1 = p1[16 + cg];
            float4 l2 = p2[cg], h2 = p2[16 + cg];
            float4 l3 = p3[cg], h3 = p3[16 + cg];
            lo.x += l1.x + l2.x + l3.x; lo.y += l1.y + l2.y + l3.y;
            lo.z += l1.z + l2.z + l3.z; lo.w += l1.w + l2.w + l3.w;
            hi.x += h1.x + h2.x + h3.x; hi.y += h1.y + h2.y + h3.y;
            hi.z += h1.z + h2.z + h3.z; hi.w += h1.w + h2.w + h3.w;
            b2[0].x = __builtin_amdgcn_rcpf(fmaxf(lo.x, SMIN));
            b2[0].y = __builtin_amdgcn_rcpf(fmaxf(lo.y, SMIN));
            b2[1].x = __builtin_amdgcn_rcpf(fmaxf(lo.z, SMIN));
            b2[1].y = __builtin_amdgcn_rcpf(fmaxf(lo.w, SMIN));
            b2[2].x = __builtin_amdgcn_rcpf(fmaxf(hi.x, SMIN));
            b2[2].y = __builtin_amdgcn_rcpf(fmaxf(hi.y, SMIN));
            b2[3].x = __builtin_amdgcn_rcpf(fmaxf(hi.z, SMIN));
            b2[3].y = __builtin_amdgcn_rcpf(fmaxf(hi.w, SMIN));
        }
        pb ^= 1;

        // ---- row phase: a_i = rcp( sum_j E_ij * b_j )  (skip after last col) ----
        if (it < NIT - 1) {
#pragma unroll
            for (int i = 0; i < 8; ++i) {
                f32x2 s2 = E[i][0] * b2[0];
                s2 += E[i][1] * b2[1];
                s2 += E[i][2] * b2[2];
                s2 += E[i][3] * b2[3];
                float s = sum16(s2.x + s2.y);
                a[i] = __builtin_amdgcn_rcpf(fmaxf(s, SMIN));
            }
        }
    }

    // ---- epilogue: out = E * a_i * b_j ----
#pragma unroll
    for (int i = 0; i < 8; ++i) {
        const float ai = a[i];
        f32x2 p0 = E[i][0] * b2[0];
        f32x2 p1 = E[i][1] * b2[1];
        f32x2 p2 = E[i][2] * b2[2];
        f32x2 p3 = E[i][3] * b2[3];
        float4 o0 = make_float4(p0.x * ai, p0.y * ai, p1.x * ai, p1.y * ai);
        float4 o1 = make_float4(p2.x * ai, p2.y * ai, p3.x * ai, p3.y * ai);
        *(float4*)(dst + (i << 7))     = o0;
        *(float4*)(dst + (i << 7) + 4) = o1;
    }
}

extern "C" void kernel_launch(void* const* d_in, const int* in_sizes, int n_in,
                              void* d_out, int out_size, void* d_ws, size_t ws_size,
                              hipStream_t stream) {
    (void)n_in; (void)d_ws; (void)ws_size; (void)out_size;
    const float* in  = (const float*)d_in[0];
    float*       out = (float*)d_out;
    const int n_mat = in_sizes[0] / (128 * 128);  // 4096
    sinkhorn_kernel<<<dim3(n_mat), dim3(256), 0, stream>>>(in, out);
}